// Round 20
// baseline (134.914 us; speedup 1.0000x reference)
//
#include <hip/hip_runtime.h>

#define S_LEN 4096
#define BATCH 2
#define DM 512
#define NH 8
#define DH 64
#define WINDOW 256

typedef __bf16 bf16x8 __attribute__((ext_vector_type(8)));
typedef float f32x4 __attribute__((ext_vector_type(4)));
typedef unsigned short u16x8 __attribute__((ext_vector_type(8)));

typedef const __attribute__((address_space(1))) unsigned int* gas_ptr;
typedef __attribute__((address_space(3))) unsigned int* las_ptr;

#define SCALE_LOG2E 0.1803368801111204f  // 0.125 * log2(e)
#define FIXED_MAX 16.0f                  // safe upper bound for log2-domain scores

// native gfx950 bf16 convert, RNE
__device__ __forceinline__ unsigned short b16(float f) {
  __bf16 h = (__bf16)f;
  return __builtin_bit_cast(unsigned short, h);
}

// One fused fp32->bf16 convert for x, qkv_w, out_w (contiguous dest regions).
#define N4_X (8192 * 512 / 4)
#define N4_QW (1536 * 512 / 4)
#define N4_OW (512 * 512 / 4)
__global__ __launch_bounds__(256) void convert_all(const float* __restrict__ x,
                                                   const float* __restrict__ qw,
                                                   const float* __restrict__ ow,
                                                   unsigned short* __restrict__ dst) {
  const int i = blockIdx.x * blockDim.x + threadIdx.x;  // exact grid, one float4 each
  const float4* src;
  int off;
  if (i < N4_X) { src = (const float4*)x; off = 0; }
  else if (i < N4_X + N4_QW) { src = (const float4*)qw; off = N4_X; }
  else { src = (const float4*)ow; off = N4_X + N4_QW; }
  const float4 v = src[i - off];
  ushort4 o;
  o.x = b16(v.x); o.y = b16(v.y); o.z = b16(v.z); o.w = b16(v.w);
  ((ushort4*)dst)[i] = o;
}

// QKV projection, 64x128 tile + XCD-pinned 1D swizzle (R14 retile mechanism +
// R17 locality mechanism, both individually proven). 1536 blocks = 6/CU for
// barrier-drain overlap; id%8 = XCD so each XCD runs 16 row-groups x 12
// col-blocks consecutively with the whole B matrix (1.5 MB) L2-resident --
// removing exactly the LLC-traffic failure mode that sank the R16 retile.
// Q (pre-scaled by SCALE_LOG2E) -> Qb, K -> Kb, V -> Vt[b][h][d][S].
__global__ __launch_bounds__(256) void gemm_qkv(const unsigned short* __restrict__ xb,
                                                const unsigned short* __restrict__ wb,
                                                const float* __restrict__ bias,
                                                unsigned short* __restrict__ Qb,
                                                unsigned short* __restrict__ Kb,
                                                unsigned short* __restrict__ Vt) {
  __shared__ __align__(16) unsigned short sA[64 * 32];
  __shared__ __align__(16) unsigned short sB[128 * 32];
  const int t = threadIdx.x;
  const int wave = t >> 6, lane = t & 63;
  const int wr = wave >> 1, wc = wave & 1;
  const int quad = lane >> 4, l16 = lane & 15;
  const int id = blockIdx.x;
  const int X = id & 7;              // XCD slot
  const int t2 = id >> 3;
  const int cb = t2 % 12;            // column block 0..11
  const int rb = (t2 / 12) * 8 + X;  // row block 0..127, pinned to XCD X
  const int m0 = rb * 64, n0 = cb * 128;

  f32x4 acc[2][4] = {};
  for (int k0 = 0; k0 < 512; k0 += 32) {
    {  // A: 64 rows x 32 k = 256 chunks, 1/thread
      const int row = t >> 2, cg = t & 3;
      const unsigned short* ga = xb + (size_t)(m0 + row) * 512 + k0 + cg * 8;
      __builtin_amdgcn_global_load_lds((gas_ptr)(const void*)ga,
                                       (las_ptr)(void*)(sA + wave * 512), 16, 0, 0);
    }
#pragma unroll
    for (int p = 0; p < 2; ++p) {  // B: 128 rows x 32 k = 512 chunks, 2/thread
      const int ci = wave * 128 + p * 64 + lane;
      const int row = ci >> 2, cg = ci & 3;
      const unsigned short* gb = wb + (size_t)(n0 + row) * 512 + k0 + cg * 8;
      __builtin_amdgcn_global_load_lds((gas_ptr)(const void*)gb,
                                       (las_ptr)(void*)(sB + wave * 1024 + p * 512), 16, 0, 0);
    }
    __syncthreads();
    bf16x8 af[2], bff[4];
#pragma unroll
    for (int i = 0; i < 2; ++i)
      af[i] = *(const bf16x8*)&sA[(wr * 32 + i * 16 + l16) * 32 + quad * 8];
#pragma unroll
    for (int j = 0; j < 4; ++j)
      bff[j] = *(const bf16x8*)&sB[(wc * 64 + j * 16 + l16) * 32 + quad * 8];
#pragma unroll
    for (int i = 0; i < 2; ++i)
#pragma unroll
      for (int j = 0; j < 4; ++j)
        acc[i][j] = __builtin_amdgcn_mfma_f32_16x16x32_bf16(af[i], bff[j], acc[i][j], 0, 0, 0);
    __syncthreads();
  }

#pragma unroll
  for (int j = 0; j < 4; ++j) {
    const int n = n0 + wc * 64 + j * 16 + l16;
    const float bv = bias[n];
#pragma unroll
    for (int i = 0; i < 2; ++i) {
      const int mr = m0 + wr * 32 + i * 16 + quad * 4;
      if (n < DM) {
#pragma unroll
        for (int r = 0; r < 4; ++r)
          Qb[(size_t)(mr + r) * DM + n] = b16((acc[i][j][r] + bv) * SCALE_LOG2E);
      } else if (n < 2 * DM) {
#pragma unroll
        for (int r = 0; r < 4; ++r)
          Kb[(size_t)(mr + r) * DM + (n - DM)] = b16(acc[i][j][r] + bv);
      } else {
        const int d = n & 63, h = (n - 2 * DM) >> 6;
#pragma unroll
        for (int r = 0; r < 4; ++r) {
          const int m = mr + r;
          const int b = m >> 12, s = m & (S_LEN - 1);
          Vt[((size_t)((b * NH + h) * DH + d)) * S_LEN + s] = b16(acc[i][j][r] + bv);
        }
      }
    }
  }
}

// Output projection, 64x128 tile, BK=32, 1D grid 512 with XCD-pinned swizzle
// (R18 win): id%8 = XCD, wout (512 KB) L2-resident per XCD.
__global__ __launch_bounds__(256) void gemm_out(const unsigned short* __restrict__ Ab,
                                                const unsigned short* __restrict__ wb,
                                                const float* __restrict__ bias,
                                                float* __restrict__ C) {
  __shared__ __align__(16) unsigned short sA[64 * 32];
  __shared__ __align__(16) unsigned short sB[128 * 32];
  const int t = threadIdx.x;
  const int wave = t >> 6, lane = t & 63;
  const int wr = wave >> 1, wc = wave & 1;
  const int quad = lane >> 4, l16 = lane & 15;
  const int id = blockIdx.x;
  const int X = id & 7;              // XCD slot
  const int t2 = id >> 3;
  const int cb = t2 % 4;             // column block 0..3
  const int rb = (t2 / 4) * 8 + X;   // row block 0..127, pinned to XCD X
  const int m0 = rb * 64, n0 = cb * 128;

  f32x4 acc[2][4] = {};
  for (int k0 = 0; k0 < 512; k0 += 32) {
    {  // A: 64 rows x 32 k = 256 chunks, 1/thread
      const int row = t >> 2, cg = t & 3;
      const unsigned short* ga = Ab + (size_t)(m0 + row) * 512 + k0 + cg * 8;
      __builtin_amdgcn_global_load_lds((gas_ptr)(const void*)ga,
                                       (las_ptr)(void*)(sA + wave * 512), 16, 0, 0);
    }
#pragma unroll
    for (int p = 0; p < 2; ++p) {  // B: 128 rows x 32 k = 512 chunks, 2/thread
      const int ci = wave * 128 + p * 64 + lane;
      const int row = ci >> 2, cg = ci & 3;
      const unsigned short* gb = wb + (size_t)(n0 + row) * 512 + k0 + cg * 8;
      __builtin_amdgcn_global_load_lds((gas_ptr)(const void*)gb,
                                       (las_ptr)(void*)(sB + wave * 1024 + p * 512), 16, 0, 0);
    }
    __syncthreads();
    bf16x8 af[2], bff[4];
#pragma unroll
    for (int i = 0; i < 2; ++i)
      af[i] = *(const bf16x8*)&sA[(wr * 32 + i * 16 + l16) * 32 + quad * 8];
#pragma unroll
    for (int j = 0; j < 4; ++j)
      bff[j] = *(const bf16x8*)&sB[(wc * 64 + j * 16 + l16) * 32 + quad * 8];
#pragma unroll
    for (int i = 0; i < 2; ++i)
#pragma unroll
      for (int j = 0; j < 4; ++j)
        acc[i][j] = __builtin_amdgcn_mfma_f32_16x16x32_bf16(af[i], bff[j], acc[i][j], 0, 0, 0);
    __syncthreads();
  }

#pragma unroll
  for (int j = 0; j < 4; ++j) {
    const int n = n0 + wc * 64 + j * 16 + l16;
    const float bv = bias[n];
#pragma unroll
    for (int i = 0; i < 2; ++i) {
      const int mr = m0 + wr * 32 + i * 16 + quad * 4;
#pragma unroll
      for (int r = 0; r < 4; ++r)
        C[(size_t)(mr + r) * DM + n] = acc[i][j][r] + bv;
    }
  }
}

// MFMA flash attention, S^T variant + XCD swizzle (exact R15/R17/R18 best).
__global__ __launch_bounds__(256) void attn_mfma(const unsigned short* __restrict__ Qb,
                                                 const unsigned short* __restrict__ Kb,
                                                 const unsigned short* __restrict__ Vt,
                                                 unsigned short* __restrict__ AO) {
  __shared__ __align__(16) unsigned short Ks[64 * 72];
  __shared__ __align__(16) unsigned short Vs[64 * 72];  // V^T chunk: [d][seq]
  __shared__ __align__(16) unsigned short Ps[64 * 72];  // P: [query][key]
  const int t = threadIdx.x;
  const int wave = t >> 6, lane = t & 63;
  const int quad = lane >> 4, l16 = lane & 15;

  // decode swizzled id: X = xcd slot, o = tile within group, h = head, b
  const int id = blockIdx.x;
  const int X = id & 7;
  const int o = (id >> 3) & 7;
  const int h = (id >> 6) & 7;
  const int b = id >> 9;
  const int g = (X - h) & 7;          // group of 8 q-tiles pinned to XCD X
  const int qt = g * 8 + o;           // q-tile index 0..63
  const int q0 = qt * 64;

  const unsigned short* Kbase = Kb + (size_t)b * S_LEN * DM + h * DH;
  const unsigned short* Vbase = Vt + (size_t)((b * NH + h) * DH) * S_LEN;

  // Q fragments from global, loop-invariant (pre-scaled by SCALE_LOG2E).
  const unsigned short* qrow =
      Qb + (size_t)(b * S_LEN + q0 + wave * 16 + l16) * DM + h * DH;
  const bf16x8 aq0 = *(const bf16x8*)(qrow + quad * 8);
  const bf16x8 aq1 = *(const bf16x8*)(qrow + 32 + quad * 8);

  const int first = (qt >= 4) ? 0 : (4 - qt);  // first valid chunk

  u16x8 kbuf[2][2], vbuf[2][2];
#define LOAD_CHUNK(c0, p)                                                      \
  do {                                                                         \
    _Pragma("unroll") for (int s = 0; s < 2; ++s) {                            \
      const int f = t + 256 * s;                                               \
      const int row = f >> 3, c8 = f & 7;                                      \
      kbuf[p][s] = *(const u16x8*)(Kbase + (size_t)((c0) + row) * DM + c8 * 8);\
      vbuf[p][s] = *(const u16x8*)(Vbase + (size_t)row * S_LEN + (c0) + c8 * 8);\
    }                                                                          \
  } while (0)

#pragma unroll
  for (int c = 0; c < 5; ++c)
    if (c == first) LOAD_CHUNK(q0 - WINDOW + c * 64, c & 1);

  float l_ = 0.f;       // scalar: all of this lane's P values share query l16
  f32x4 O[4] = {};      // O^T: row = d = nt*16+quad*4+r, col = query = l16

#pragma unroll
  for (int c = 0; c < 5; ++c) {
    if (c < first) continue;  // block-uniform
    const int c0 = q0 - WINDOW + c * 64;
    __syncthreads();  // prior chunk's LDS reads complete before overwrite
#pragma unroll
    for (int s = 0; s < 2; ++s) {
      const int f = t + 256 * s;
      const int row = f >> 3, c8 = f & 7;
      *(u16x8*)&Ks[row * 72 + c8 * 8] = kbuf[c & 1][s];
      *(u16x8*)&Vs[row * 72 + c8 * 8] = vbuf[c & 1][s];
    }
    if (c < 4) LOAD_CHUNK(c0 + 64, (c + 1) & 1);  // prefetch next chunk
    __syncthreads();

    // S^T = K Q^T: A = K-frag (rows = keys), B = Q-frag (cols = queries)
    f32x4 sc[4];
#pragma unroll
    for (int nt = 0; nt < 4; ++nt) {
      bf16x8 bk0 = *(const bf16x8*)&Ks[(nt * 16 + l16) * 72 + quad * 8];
      bf16x8 bk1 = *(const bf16x8*)&Ks[(nt * 16 + l16) * 72 + 32 + quad * 8];
      f32x4 z = {};
      z = __builtin_amdgcn_mfma_f32_16x16x32_bf16(bk0, aq0, z, 0, 0, 0);
      sc[nt] = __builtin_amdgcn_mfma_f32_16x16x32_bf16(bk1, aq1, z, 0, 0, 0);
    }

    // p = exp2(s - 16); boundary masks with key/query roles per S^T layout.
    const int iiq = wave * 16 + l16;  // query (local)
#pragma unroll
    for (int nt = 0; nt < 4; ++nt) {
#pragma unroll
      for (int r = 0; r < 4; ++r) {
        const int jjk = nt * 16 + quad * 4 + r;  // key (local)
        float p = exp2f(sc[nt][r] - FIXED_MAX);
        if (c == 0) p = (jjk >= iiq) ? p : 0.f;
        if (c == 4) p = (jjk <= iiq) ? p : 0.f;
        sc[nt][r] = p;
        l_ += p;
      }
      ushort4 pk;
      pk.x = b16(sc[nt][0]);
      pk.y = b16(sc[nt][1]);
      pk.z = b16(sc[nt][2]);
      pk.w = b16(sc[nt][3]);
      *(ushort4*)&Ps[(wave * 16 + l16) * 72 + nt * 16 + quad * 4] = pk;
    }

    // B-frags of P^T: lane (quad,l16) reads Ps[query l16][keys quad*8..+7]
    const bf16x8 bp0 = *(const bf16x8*)&Ps[(wave * 16 + l16) * 72 + quad * 8];
    const bf16x8 bp1 = *(const bf16x8*)&Ps[(wave * 16 + l16) * 72 + 32 + quad * 8];

    // O^T += V^T P^T: A = V^T frag (rows = d), B = P^T
#pragma unroll
    for (int nt = 0; nt < 4; ++nt) {
      bf16x8 bv0 = *(const bf16x8*)&Vs[(nt * 16 + l16) * 72 + quad * 8];
      bf16x8 bv1 = *(const bf16x8*)&Vs[(nt * 16 + l16) * 72 + 32 + quad * 8];
      O[nt] = __builtin_amdgcn_mfma_f32_16x16x32_bf16(bv0, bp0, O[nt], 0, 0, 0);
      O[nt] = __builtin_amdgcn_mfma_f32_16x16x32_bf16(bv1, bp1, O[nt], 0, 0, 0);
    }
  }

  // denominator: reduce partials across the 4 quads (lane bits 4,5)
  l_ += __shfl_xor(l_, 16);
  l_ += __shfl_xor(l_, 32);
  const float linv = 1.f / l_;

  // O^T C-layout: lane's 4 regs are d-consecutive -> packed 8B stores
  unsigned short* aoRow =
      AO + (size_t)(b * S_LEN + q0 + wave * 16 + l16) * DM + h * DH;
#pragma unroll
  for (int nt = 0; nt < 4; ++nt) {
    ushort4 o4;
    o4.x = b16(O[nt][0] * linv);
    o4.y = b16(O[nt][1] * linv);
    o4.z = b16(O[nt][2] * linv);
    o4.w = b16(O[nt][3] * linv);
    *(ushort4*)(aoRow + nt * 16 + quad * 4) = o4;
  }
}

extern "C" void kernel_launch(void* const* d_in, const int* in_sizes, int n_in,
                              void* d_out, int out_size, void* d_ws, size_t ws_size,
                              hipStream_t stream) {
  const float* x = (const float*)d_in[0];
  const float* qkv_w = (const float*)d_in[1];
  const float* qkv_b = (const float*)d_in[2];
  const float* out_w = (const float*)d_in[3];
  const float* out_b = (const float*)d_in[4];
  float* out = (float*)d_out;

  const int M = BATCH * S_LEN;  // 8192
  unsigned short* ws = (unsigned short*)d_ws;
  unsigned short* xb   = ws;                      // 8192*512
  unsigned short* wqkv = xb + (size_t)M * DM;     // 1536*512
  unsigned short* wout = wqkv + 3 * DM * DM;      // 512*512
  unsigned short* Qb   = wout + DM * DM;          // 8192*512
  unsigned short* Kb   = Qb + (size_t)M * DM;     // 8192*512
  unsigned short* Vt   = Kb + (size_t)M * DM;     // 2*8*64*4096
  unsigned short* AO   = Vt + (size_t)M * DM;     // 8192*512

  convert_all<<<(N4_X + N4_QW + N4_OW) / 256, 256, 0, stream>>>(x, qkv_w, out_w, xb);

  gemm_qkv<<<1536, 256, 0, stream>>>(xb, wqkv, qkv_b, Qb, Kb, Vt);

  attn_mfma<<<1024, 256, 0, stream>>>(Qb, Kb, Vt, AO);

  gemm_out<<<512, 256, 0, stream>>>(AO, wout, out_b, out);
}

// Round 21
// 126.886 us; speedup vs baseline: 1.0633x; 1.0633x over previous
//
#include <hip/hip_runtime.h>

#define S_LEN 4096
#define BATCH 2
#define DM 512
#define NH 8
#define DH 64
#define WINDOW 256

typedef __bf16 bf16x8 __attribute__((ext_vector_type(8)));
typedef float f32x4 __attribute__((ext_vector_type(4)));
typedef unsigned short u16x8 __attribute__((ext_vector_type(8)));

typedef const __attribute__((address_space(1))) unsigned int* gas_ptr;
typedef __attribute__((address_space(3))) unsigned int* las_ptr;

#define SCALE_LOG2E 0.1803368801111204f  // 0.125 * log2(e)
#define FIXED_MAX 16.0f                  // safe upper bound for log2-domain scores

// native gfx950 bf16 convert, RNE
__device__ __forceinline__ unsigned short b16(float f) {
  __bf16 h = (__bf16)f;
  return __builtin_bit_cast(unsigned short, h);
}

// One fused fp32->bf16 convert for x, qkv_w, out_w (contiguous dest regions).
#define N4_X (8192 * 512 / 4)
#define N4_QW (1536 * 512 / 4)
#define N4_OW (512 * 512 / 4)
__global__ __launch_bounds__(256) void convert_all(const float* __restrict__ x,
                                                   const float* __restrict__ qw,
                                                   const float* __restrict__ ow,
                                                   unsigned short* __restrict__ dst) {
  const int i = blockIdx.x * blockDim.x + threadIdx.x;  // exact grid, one float4 each
  const float4* src;
  int off;
  if (i < N4_X) { src = (const float4*)x; off = 0; }
  else if (i < N4_X + N4_QW) { src = (const float4*)qw; off = N4_X; }
  else { src = (const float4*)ow; off = N4_X + N4_QW; }
  const float4 v = src[i - off];
  ushort4 o;
  o.x = b16(v.x); o.y = b16(v.y); o.z = b16(v.z); o.w = b16(v.w);
  ((ushort4*)dst)[i] = o;
}

// m97-style K-loop (proven R4/R8 structure): C128x128 = A[128x512]*B[128x512]^T,
// BK=32, global_load_lds width-16 staging, 16x16x32 MFMA, 4 waves.
__device__ __forceinline__ void gemm_core(const unsigned short* __restrict__ A,
                                          const unsigned short* __restrict__ Bm,
                                          int m0, int n0,
                                          unsigned short* sA, unsigned short* sB,
                                          f32x4 acc[4][4]) {
  const int t = threadIdx.x;
  const int wave = t >> 6, lane = t & 63;
  const int wr = wave >> 1, wc = wave & 1;
  const int quad = lane >> 4, l16 = lane & 15;

  for (int k0 = 0; k0 < 512; k0 += 32) {
#pragma unroll
    for (int p = 0; p < 2; ++p) {
      const int ci = wave * 128 + p * 64 + lane;   // 16B chunk id, lane-contiguous
      const int row = ci >> 2, cg = ci & 3;
      const unsigned short* ga = A + (size_t)(m0 + row) * 512 + k0 + cg * 8;
      __builtin_amdgcn_global_load_lds((gas_ptr)(const void*)ga,
                                       (las_ptr)(void*)(sA + wave * 1024 + p * 512), 16, 0, 0);
      const unsigned short* gb = Bm + (size_t)(n0 + row) * 512 + k0 + cg * 8;
      __builtin_amdgcn_global_load_lds((gas_ptr)(const void*)gb,
                                       (las_ptr)(void*)(sB + wave * 1024 + p * 512), 16, 0, 0);
    }
    __syncthreads();
    bf16x8 af[4], bff[4];
#pragma unroll
    for (int i = 0; i < 4; ++i)
      af[i] = *(const bf16x8*)&sA[(wr * 64 + i * 16 + l16) * 32 + quad * 8];
#pragma unroll
    for (int j = 0; j < 4; ++j)
      bff[j] = *(const bf16x8*)&sB[(wc * 64 + j * 16 + l16) * 32 + quad * 8];
#pragma unroll
    for (int i = 0; i < 4; ++i)
#pragma unroll
      for (int j = 0; j < 4; ++j)
        acc[i][j] = __builtin_amdgcn_mfma_f32_16x16x32_bf16(af[i], bff[j], acc[i][j], 0, 0, 0);
    __syncthreads();
  }
}

// QKV projection, 128x128 tile, XCD-pinned 1D swizzle (R17 win): id%8 = XCD,
// each XCD runs one row-block's 12 column-blocks consecutively -> A-tile and
// whole B matrix (1.5 MB) L2-resident per XCD.
__global__ __launch_bounds__(256) void gemm_qkv(const unsigned short* __restrict__ xb,
                                                const unsigned short* __restrict__ wb,
                                                const float* __restrict__ bias,
                                                unsigned short* __restrict__ Qb,
                                                unsigned short* __restrict__ Kb,
                                                unsigned short* __restrict__ Vt) {
  __shared__ __align__(16) unsigned short sA[128 * 32];
  __shared__ __align__(16) unsigned short sB[128 * 32];
  f32x4 acc[4][4] = {};
  const int id = blockIdx.x;
  const int X = id & 7;          // XCD slot
  const int t2 = id >> 3;
  const int cb = t2 % 12;        // column block 0..11
  const int rb = (t2 / 12) * 8 + X;  // row block 0..63, pinned to XCD X
  const int m0 = rb * 128, n0 = cb * 128;
  gemm_core(xb, wb, m0, n0, sA, sB, acc);

  const int t = threadIdx.x;
  const int wave = t >> 6, lane = t & 63;
  const int wr = wave >> 1, wc = wave & 1;
  const int quad = lane >> 4, l16 = lane & 15;
#pragma unroll
  for (int j = 0; j < 4; ++j) {
    const int n = n0 + wc * 64 + j * 16 + l16;
    const float bv = bias[n];
#pragma unroll
    for (int i = 0; i < 4; ++i) {
      const int mr = m0 + wr * 64 + i * 16 + quad * 4;
      if (n < DM) {
#pragma unroll
        for (int r = 0; r < 4; ++r)
          Qb[(size_t)(mr + r) * DM + n] = b16((acc[i][j][r] + bv) * SCALE_LOG2E);
      } else if (n < 2 * DM) {
#pragma unroll
        for (int r = 0; r < 4; ++r)
          Kb[(size_t)(mr + r) * DM + (n - DM)] = b16(acc[i][j][r] + bv);
      } else {
        const int d = n & 63, h = (n - 2 * DM) >> 6;
#pragma unroll
        for (int r = 0; r < 4; ++r) {
          const int m = mr + r;
          const int b = m >> 12, s = m & (S_LEN - 1);
          Vt[((size_t)((b * NH + h) * DH + d)) * S_LEN + s] = b16(acc[i][j][r] + bv);
        }
      }
    }
  }
}

// Output projection, 64x128 tile, BK=32, 1D grid 512 with XCD-pinned swizzle
// (R18 win): id%8 = XCD, wout (512 KB) L2-resident per XCD.
__global__ __launch_bounds__(256) void gemm_out(const unsigned short* __restrict__ Ab,
                                                const unsigned short* __restrict__ wb,
                                                const float* __restrict__ bias,
                                                float* __restrict__ C) {
  __shared__ __align__(16) unsigned short sA[64 * 32];
  __shared__ __align__(16) unsigned short sB[128 * 32];
  const int t = threadIdx.x;
  const int wave = t >> 6, lane = t & 63;
  const int wr = wave >> 1, wc = wave & 1;
  const int quad = lane >> 4, l16 = lane & 15;
  const int id = blockIdx.x;
  const int X = id & 7;              // XCD slot
  const int t2 = id >> 3;
  const int cb = t2 % 4;             // column block 0..3
  const int rb = (t2 / 4) * 8 + X;   // row block 0..127, pinned to XCD X
  const int m0 = rb * 64, n0 = cb * 128;

  f32x4 acc[2][4] = {};
  for (int k0 = 0; k0 < 512; k0 += 32) {
    {  // A: 64 rows x 32 k = 256 chunks, 1/thread
      const int row = t >> 2, cg = t & 3;
      const unsigned short* ga = Ab + (size_t)(m0 + row) * 512 + k0 + cg * 8;
      __builtin_amdgcn_global_load_lds((gas_ptr)(const void*)ga,
                                       (las_ptr)(void*)(sA + wave * 512), 16, 0, 0);
    }
#pragma unroll
    for (int p = 0; p < 2; ++p) {  // B: 128 rows x 32 k = 512 chunks, 2/thread
      const int ci = wave * 128 + p * 64 + lane;
      const int row = ci >> 2, cg = ci & 3;
      const unsigned short* gb = wb + (size_t)(n0 + row) * 512 + k0 + cg * 8;
      __builtin_amdgcn_global_load_lds((gas_ptr)(const void*)gb,
                                       (las_ptr)(void*)(sB + wave * 1024 + p * 512), 16, 0, 0);
    }
    __syncthreads();
    bf16x8 af[2], bff[4];
#pragma unroll
    for (int i = 0; i < 2; ++i)
      af[i] = *(const bf16x8*)&sA[(wr * 32 + i * 16 + l16) * 32 + quad * 8];
#pragma unroll
    for (int j = 0; j < 4; ++j)
      bff[j] = *(const bf16x8*)&sB[(wc * 64 + j * 16 + l16) * 32 + quad * 8];
#pragma unroll
    for (int i = 0; i < 2; ++i)
#pragma unroll
      for (int j = 0; j < 4; ++j)
        acc[i][j] = __builtin_amdgcn_mfma_f32_16x16x32_bf16(af[i], bff[j], acc[i][j], 0, 0, 0);
    __syncthreads();
  }

#pragma unroll
  for (int j = 0; j < 4; ++j) {
    const int n = n0 + wc * 64 + j * 16 + l16;
    const float bv = bias[n];
#pragma unroll
    for (int i = 0; i < 2; ++i) {
      const int mr = m0 + wr * 32 + i * 16 + quad * 4;
#pragma unroll
      for (int r = 0; r < 4; ++r)
        C[(size_t)(mr + r) * DM + n] = acc[i][j][r] + bv;
    }
  }
}

// MFMA flash attention, S^T variant + XCD swizzle (exact R15/R17/R18 best).
__global__ __launch_bounds__(256) void attn_mfma(const unsigned short* __restrict__ Qb,
                                                 const unsigned short* __restrict__ Kb,
                                                 const unsigned short* __restrict__ Vt,
                                                 unsigned short* __restrict__ AO) {
  __shared__ __align__(16) unsigned short Ks[64 * 72];
  __shared__ __align__(16) unsigned short Vs[64 * 72];  // V^T chunk: [d][seq]
  __shared__ __align__(16) unsigned short Ps[64 * 72];  // P: [query][key]
  const int t = threadIdx.x;
  const int wave = t >> 6, lane = t & 63;
  const int quad = lane >> 4, l16 = lane & 15;

  // decode swizzled id: X = xcd slot, o = tile within group, h = head, b
  const int id = blockIdx.x;
  const int X = id & 7;
  const int o = (id >> 3) & 7;
  const int h = (id >> 6) & 7;
  const int b = id >> 9;
  const int g = (X - h) & 7;          // group of 8 q-tiles pinned to XCD X
  const int qt = g * 8 + o;           // q-tile index 0..63
  const int q0 = qt * 64;

  const unsigned short* Kbase = Kb + (size_t)b * S_LEN * DM + h * DH;
  const unsigned short* Vbase = Vt + (size_t)((b * NH + h) * DH) * S_LEN;

  // Q fragments from global, loop-invariant (pre-scaled by SCALE_LOG2E).
  const unsigned short* qrow =
      Qb + (size_t)(b * S_LEN + q0 + wave * 16 + l16) * DM + h * DH;
  const bf16x8 aq0 = *(const bf16x8*)(qrow + quad * 8);
  const bf16x8 aq1 = *(const bf16x8*)(qrow + 32 + quad * 8);

  const int first = (qt >= 4) ? 0 : (4 - qt);  // first valid chunk

  u16x8 kbuf[2][2], vbuf[2][2];
#define LOAD_CHUNK(c0, p)                                                      \
  do {                                                                         \
    _Pragma("unroll") for (int s = 0; s < 2; ++s) {                            \
      const int f = t + 256 * s;                                               \
      const int row = f >> 3, c8 = f & 7;                                      \
      kbuf[p][s] = *(const u16x8*)(Kbase + (size_t)((c0) + row) * DM + c8 * 8);\
      vbuf[p][s] = *(const u16x8*)(Vbase + (size_t)row * S_LEN + (c0) + c8 * 8);\
    }                                                                          \
  } while (0)

#pragma unroll
  for (int c = 0; c < 5; ++c)
    if (c == first) LOAD_CHUNK(q0 - WINDOW + c * 64, c & 1);

  float l_ = 0.f;       // scalar: all of this lane's P values share query l16
  f32x4 O[4] = {};      // O^T: row = d = nt*16+quad*4+r, col = query = l16

#pragma unroll
  for (int c = 0; c < 5; ++c) {
    if (c < first) continue;  // block-uniform
    const int c0 = q0 - WINDOW + c * 64;
    __syncthreads();  // prior chunk's LDS reads complete before overwrite
#pragma unroll
    for (int s = 0; s < 2; ++s) {
      const int f = t + 256 * s;
      const int row = f >> 3, c8 = f & 7;
      *(u16x8*)&Ks[row * 72 + c8 * 8] = kbuf[c & 1][s];
      *(u16x8*)&Vs[row * 72 + c8 * 8] = vbuf[c & 1][s];
    }
    if (c < 4) LOAD_CHUNK(c0 + 64, (c + 1) & 1);  // prefetch next chunk
    __syncthreads();

    // S^T = K Q^T: A = K-frag (rows = keys), B = Q-frag (cols = queries)
    f32x4 sc[4];
#pragma unroll
    for (int nt = 0; nt < 4; ++nt) {
      bf16x8 bk0 = *(const bf16x8*)&Ks[(nt * 16 + l16) * 72 + quad * 8];
      bf16x8 bk1 = *(const bf16x8*)&Ks[(nt * 16 + l16) * 72 + 32 + quad * 8];
      f32x4 z = {};
      z = __builtin_amdgcn_mfma_f32_16x16x32_bf16(bk0, aq0, z, 0, 0, 0);
      sc[nt] = __builtin_amdgcn_mfma_f32_16x16x32_bf16(bk1, aq1, z, 0, 0, 0);
    }

    // p = exp2(s - 16); boundary masks with key/query roles per S^T layout.
    const int iiq = wave * 16 + l16;  // query (local)
#pragma unroll
    for (int nt = 0; nt < 4; ++nt) {
#pragma unroll
      for (int r = 0; r < 4; ++r) {
        const int jjk = nt * 16 + quad * 4 + r;  // key (local)
        float p = exp2f(sc[nt][r] - FIXED_MAX);
        if (c == 0) p = (jjk >= iiq) ? p : 0.f;
        if (c == 4) p = (jjk <= iiq) ? p : 0.f;
        sc[nt][r] = p;
        l_ += p;
      }
      ushort4 pk;
      pk.x = b16(sc[nt][0]);
      pk.y = b16(sc[nt][1]);
      pk.z = b16(sc[nt][2]);
      pk.w = b16(sc[nt][3]);
      *(ushort4*)&Ps[(wave * 16 + l16) * 72 + nt * 16 + quad * 4] = pk;
    }

    // B-frags of P^T: lane (quad,l16) reads Ps[query l16][keys quad*8..+7]
    const bf16x8 bp0 = *(const bf16x8*)&Ps[(wave * 16 + l16) * 72 + quad * 8];
    const bf16x8 bp1 = *(const bf16x8*)&Ps[(wave * 16 + l16) * 72 + 32 + quad * 8];

    // O^T += V^T P^T: A = V^T frag (rows = d), B = P^T
#pragma unroll
    for (int nt = 0; nt < 4; ++nt) {
      bf16x8 bv0 = *(const bf16x8*)&Vs[(nt * 16 + l16) * 72 + quad * 8];
      bf16x8 bv1 = *(const bf16x8*)&Vs[(nt * 16 + l16) * 72 + 32 + quad * 8];
      O[nt] = __builtin_amdgcn_mfma_f32_16x16x32_bf16(bv0, bp0, O[nt], 0, 0, 0);
      O[nt] = __builtin_amdgcn_mfma_f32_16x16x32_bf16(bv1, bp1, O[nt], 0, 0, 0);
    }
  }

  // denominator: reduce partials across the 4 quads (lane bits 4,5)
  l_ += __shfl_xor(l_, 16);
  l_ += __shfl_xor(l_, 32);
  const float linv = 1.f / l_;

  // O^T C-layout: lane's 4 regs are d-consecutive -> packed 8B stores
  unsigned short* aoRow =
      AO + (size_t)(b * S_LEN + q0 + wave * 16 + l16) * DM + h * DH;
#pragma unroll
  for (int nt = 0; nt < 4; ++nt) {
    ushort4 o4;
    o4.x = b16(O[nt][0] * linv);
    o4.y = b16(O[nt][1] * linv);
    o4.z = b16(O[nt][2] * linv);
    o4.w = b16(O[nt][3] * linv);
    *(ushort4*)(aoRow + nt * 16 + quad * 4) = o4;
  }
}

extern "C" void kernel_launch(void* const* d_in, const int* in_sizes, int n_in,
                              void* d_out, int out_size, void* d_ws, size_t ws_size,
                              hipStream_t stream) {
  const float* x = (const float*)d_in[0];
  const float* qkv_w = (const float*)d_in[1];
  const float* qkv_b = (const float*)d_in[2];
  const float* out_w = (const float*)d_in[3];
  const float* out_b = (const float*)d_in[4];
  float* out = (float*)d_out;

  const int M = BATCH * S_LEN;  // 8192
  unsigned short* ws = (unsigned short*)d_ws;
  unsigned short* xb   = ws;                      // 8192*512
  unsigned short* wqkv = xb + (size_t)M * DM;     // 1536*512
  unsigned short* wout = wqkv + 3 * DM * DM;      // 512*512
  unsigned short* Qb   = wout + DM * DM;          // 8192*512
  unsigned short* Kb   = Qb + (size_t)M * DM;     // 8192*512
  unsigned short* Vt   = Kb + (size_t)M * DM;     // 2*8*64*4096
  unsigned short* AO   = Vt + (size_t)M * DM;     // 8192*512

  convert_all<<<(N4_X + N4_QW + N4_OW) / 256, 256, 0, stream>>>(x, qkv_w, out_w, xb);

  gemm_qkv<<<768, 256, 0, stream>>>(xb, wqkv, qkv_b, Qb, Kb, Vt);

  attn_mfma<<<1024, 256, 0, stream>>>(Qb, Kb, Vt, AO);

  gemm_out<<<512, 256, 0, stream>>>(AO, wout, out_b, out);
}